// Round 4
// baseline (403.921 us; speedup 1.0000x reference)
//
#include <hip/hip_runtime.h>

typedef _Float16 f16;
typedef _Float16 f16x4 __attribute__((ext_vector_type(4)));
typedef _Float16 f16x8 __attribute__((ext_vector_type(8)));
typedef float    f32x4 __attribute__((ext_vector_type(4)));

#define DEV static __device__ __forceinline__

DEV f32x4 mfma16(f16x8 a, f16x8 b, f32x4 c) {
    return __builtin_amdgcn_mfma_f32_16x16x32_f16(a, b, c, 0, 0, 0);
}

// async global->LDS, 16B per lane, dest = wave-uniform base + lane*16
DEV void gload16(const f16* g, f16* l) {
    __builtin_amdgcn_global_load_lds(
        (const __attribute__((address_space(1))) unsigned int*)g,
        (__attribute__((address_space(3))) unsigned int*)l,
        16, 0, 0);
}

// B=4, S=1024, D=768, H=12, DH=64, R=129 (padded 160/168 for k-steps)

// ---------------------------------------------------------------- weight convert
struct ConvArgs {
    const float* src[5];
    f16*         dst[5];
};

// weights wq,wk,wv,wo (147456 float4 each) + embK (24768 float4)
__global__ __launch_bounds__(256) void k_convw(ConvArgs a) {
    const int seg[6] = {0, 147456, 294912, 442368, 589824, 614592};
    for (int i = blockIdx.x * 256 + threadIdx.x; i < 614592; i += gridDim.x * 256) {
        int s = 0;
        while (i >= seg[s + 1]) s++;
        const int j = i - seg[s];
        const float4 v = ((const float4*)a.src[s])[j];
        f16x4 o;
        o[0] = (f16)v.x; o[1] = (f16)v.y; o[2] = (f16)v.z; o[3] = (f16)v.w;
        ((f16x4*)a.dst[s])[j] = o;
    }
}

// embVt[h][dh][r] = embV[r, h*64+dh] for r<129 else 0
__global__ __launch_bounds__(256) void k_embvt(const float* __restrict__ embV,
                                               f16* __restrict__ dst) {
    const int idx = blockIdx.x * 256 + threadIdx.x;
    if (idx >= 12 * 64 * 160) return;
    const int r  = idx % 160;
    const int dh = (idx / 160) % 64;
    const int h  = idx / (160 * 64);
    float v = 0.f;
    if (r < 129) v = embV[r * 768 + h * 64 + dh];
    dst[idx] = (f16)v;
}

// ---------------------------------------------------------------- QKV GEMM
// 128x128 tile, BK=32. A (activations) is fp32 in global: load float4 x4,
// convert in VGPR, ds_write_b128 into the same XOR-swizzled slots the async
// path uses. B (weights, f16) stays async global_load_lds width=16.
// Swizzle: slot (r,c) holds global chunk c^s(r), s(r)=((r)^(r>>2))&3
// (periodic in r mod 16); reader chunk = quad ^ s(l16).
__global__ __launch_bounds__(256) void k_gemm_qkv(
    const float* __restrict__ xq, const float* __restrict__ xk, const float* __restrict__ xv,
    const f16* __restrict__ wq, const f16* __restrict__ wk, const f16* __restrict__ wv,
    const float* __restrict__ bq, const float* __restrict__ bk, const float* __restrict__ bv,
    f16* __restrict__ Qh, f16* __restrict__ Kh, f16* __restrict__ Vh) {
    __shared__ __align__(16) f16 As[128 * 32];
    __shared__ __align__(16) f16 Bs[128 * 32];

    const int t  = blockIdx.y / 6;           // 0:Q 1:K 2:V
    const int n0 = (blockIdx.y % 6) * 128;   // within 768
    const int m0 = blockIdx.x * 128;
    const float* X    = (t == 0) ? xq : (t == 1) ? xk : xv;
    const f16*   W    = (t == 0) ? wq : (t == 1) ? wk : wv;
    const float* bias = (t == 0) ? bq : (t == 1) ? bk : bv;

    const int tid = threadIdx.x;
    const int w = tid >> 6, l = tid & 63, quad = l >> 4, l16 = l & 15;
    const int wr = w >> 1, wc = w & 1;
    const int rl = l >> 2, cc = l & 3;
    const int csrc = (cc ^ ((rl ^ (rl >> 2)) & 3)) * 8;
    const float* gA = X + (size_t)(m0 + w * 32 + rl) * 768 + csrc;
    const f16*   gB = W + (size_t)(n0 + w * 32 + rl) * 768 + csrc;
    f16* lA0 = As + (w * 32) * 32;
    f16* lA1 = As + (w * 32 + 16) * 32;
    f16* lB0 = Bs + (w * 32) * 32;
    f16* lB1 = Bs + (w * 32 + 16) * 32;
    const int xsw = (quad ^ ((l16 ^ (l16 >> 2)) & 3)) * 8;

    f32x4 acc[4][4] = {};

    for (int k0 = 0; k0 < 768; k0 += 32) {
        const float4 a00 = *(const float4*)(gA + k0);
        const float4 a01 = *(const float4*)(gA + k0 + 4);
        const float4 a10 = *(const float4*)(gA + k0 + 16 * 768);
        const float4 a11 = *(const float4*)(gA + k0 + 16 * 768 + 4);
        __syncthreads();
        f16x8 pa0, pa1;
        pa0[0] = (f16)a00.x; pa0[1] = (f16)a00.y; pa0[2] = (f16)a00.z; pa0[3] = (f16)a00.w;
        pa0[4] = (f16)a01.x; pa0[5] = (f16)a01.y; pa0[6] = (f16)a01.z; pa0[7] = (f16)a01.w;
        pa1[0] = (f16)a10.x; pa1[1] = (f16)a10.y; pa1[2] = (f16)a10.z; pa1[3] = (f16)a10.w;
        pa1[4] = (f16)a11.x; pa1[5] = (f16)a11.y; pa1[6] = (f16)a11.z; pa1[7] = (f16)a11.w;
        ((f16x8*)lA0)[l] = pa0;
        ((f16x8*)lA1)[l] = pa1;
        gload16(gB + k0, lB0);
        gload16(gB + k0 + 16 * 768, lB1);
        __syncthreads();
        f16x8 af[4], bf[4];
#pragma unroll
        for (int i = 0; i < 4; i++)
            af[i] = *(const f16x8*)(As + (wr * 64 + i * 16 + l16) * 32 + xsw);
#pragma unroll
        for (int i = 0; i < 4; i++)
            bf[i] = *(const f16x8*)(Bs + (wc * 64 + i * 16 + l16) * 32 + xsw);
#pragma unroll
        for (int i = 0; i < 4; i++)
#pragma unroll
            for (int j = 0; j < 4; j++)
                acc[i][j] = mfma16(af[i], bf[j], acc[i][j]);
    }

    // epilogue: C/D layout col=lane&15, row=quad*4+reg; all t store [bh][s][dh]
    f16* dst = (t == 0) ? Qh : (t == 1) ? Kh : Vh;
#pragma unroll
    for (int j = 0; j < 4; j++) {
        const int   nj = n0 + wc * 64 + j * 16 + l16;  // 0..767
        const float bb = bias[nj];
        const int   h = nj >> 6, dh = nj & 63;
#pragma unroll
        for (int i = 0; i < 4; i++) {
            const int mb = m0 + wr * 64 + i * 16 + quad * 4;
            const int b = mb >> 10, s = mb & 1023;
            const int base = ((b * 12 + h) * 1024 + s) * 64 + dh;
#pragma unroll
            for (int r = 0; r < 4; r++)
                dst[base + r * 64] = (f16)(acc[i][j][r] + bb);
        }
    }
}

// ---------------------------------------------------------------- V transpose
// Vh[bh][s][dh] -> Vt[bh][dh][s], 64x64 tiles via LDS (stride 72 pad)
__global__ __launch_bounds__(256) void k_vt(const f16* __restrict__ Vh,
                                            f16* __restrict__ Vt) {
    __shared__ __align__(16) f16 ld[64 * 72];
    const int s0 = blockIdx.x * 64, bh = blockIdx.y;
    const int tid = threadIdx.x;
    const int sr = tid >> 2;   // s-row 0..63 (coalesced global read)
    const int ch = tid & 3;    // 16-col chunk
    const f16* src = Vh + ((size_t)bh * 1024 + s0 + sr) * 64 + ch * 16;
    const f16x8 v0 = *(const f16x8*)(src);
    const f16x8 v1 = *(const f16x8*)(src + 8);
#pragma unroll
    for (int c = 0; c < 8; c++) ld[(ch * 16 + c) * 72 + sr] = v0[c];
#pragma unroll
    for (int c = 0; c < 8; c++) ld[(ch * 16 + 8 + c) * 72 + sr] = v1[c];
    __syncthreads();
    const int dh = tid >> 2;
    f16* dst = Vt + ((size_t)bh * 64 + dh) * 1024 + s0 + ch * 16;
    *(f16x8*)(dst)     = *(const f16x8*)(ld + dh * 72 + ch * 16);
    *(f16x8*)(dst + 8) = *(const f16x8*)(ld + dh * 72 + ch * 16 + 8);
}

// ---------------------------------------------------------------- out GEMM
// 64m x 128n tiles -> grid 64x6 = 384 blocks. Wave: 32m x 64n, acc[2][4].
__global__ __launch_bounds__(256) void k_gemm_out(
    const f16* __restrict__ Xin, const f16* __restrict__ Win,
    const float* __restrict__ bias, float* __restrict__ out) {
    __shared__ __align__(16) f16 As[64 * 32];
    __shared__ __align__(16) f16 Bs[128 * 32];

    const int m0 = blockIdx.x * 64;
    const int n0 = blockIdx.y * 128;
    const int tid = threadIdx.x;
    const int w = tid >> 6, l = tid & 63, quad = l >> 4, l16 = l & 15;
    const int mh = w & 1, nh = w >> 1;
    const int rl = l >> 2, cc = l & 3;
    const int csrc = (cc ^ ((rl ^ (rl >> 2)) & 3)) * 8;
    const f16* gA = Xin + (size_t)(m0 + w * 16 + rl) * 768 + csrc;
    const f16* gB = Win + (size_t)(n0 + w * 32 + rl) * 768 + csrc;
    f16* lA  = As + (w * 16) * 32;
    f16* lB0 = Bs + (w * 32) * 32;
    f16* lB1 = Bs + (w * 32 + 16) * 32;
    const int xsw = (quad ^ ((l16 ^ (l16 >> 2)) & 3)) * 8;

    f32x4 acc[2][4] = {};

    for (int k0 = 0; k0 < 768; k0 += 32) {
        __syncthreads();
        gload16(gA + k0, lA);
        gload16(gB + k0, lB0);
        gload16(gB + k0 + 16 * 768, lB1);
        __syncthreads();
        f16x8 af[2], bf[4];
#pragma unroll
        for (int i = 0; i < 2; i++)
            af[i] = *(const f16x8*)(As + (mh * 32 + i * 16 + l16) * 32 + xsw);
#pragma unroll
        for (int j = 0; j < 4; j++)
            bf[j] = *(const f16x8*)(Bs + (nh * 64 + j * 16 + l16) * 32 + xsw);
#pragma unroll
        for (int i = 0; i < 2; i++)
#pragma unroll
            for (int j = 0; j < 4; j++)
                acc[i][j] = mfma16(af[i], bf[j], acc[i][j]);
    }

#pragma unroll
    for (int j = 0; j < 4; j++) {
        const int   nj = n0 + nh * 64 + j * 16 + l16;
        const float bb = bias[nj];
#pragma unroll
        for (int i = 0; i < 2; i++) {
            const int mb = m0 + mh * 32 + i * 16 + quad * 4;
#pragma unroll
            for (int r = 0; r < 4; r++)
                out[(size_t)(mb + r) * 768 + nj] = acc[i][j][r] + bb;
        }
    }
}

// ---------------------------------------------------------------- fused attention
// One block = (b,h, 16 q-rows). No-max softmax fused into score phase.
// Band-aware rel add: a 16-col chunk fully below/above the +-64 band
// (wave-uniform test) uses register rlo/rhi instead of the LDS gather.
// relw stride 168 (4-way worst case in residual gathers, was 8-way at 160).
constexpr int SCP = 1032;   // score row stride (f16)
constexpr int RST = 168;    // relw row stride (f16)

__global__ __launch_bounds__(256) void k_attn(
    const f16* __restrict__ Qh, const f16* __restrict__ Kh, const f16* __restrict__ Vt,
    const f16* __restrict__ embK, const f16* __restrict__ embVt,
    float* __restrict__ attn, f16* __restrict__ ctx) {
    __shared__ __align__(16) f16 sc[16 * SCP];     // 33,024 B
    __shared__ __align__(16) f16 relw[16 * RST];   //  5,376 B
    __shared__ float red[3][4][16];
    __shared__ float invs[16], tl0[16], tl1[16];

    const int qt = blockIdx.x, bh = blockIdx.y;
    const int b = bh / 12, h = bh % 12;
    const int q0 = qt * 16;
    const int tid = threadIdx.x;
    const int w = tid >> 6, l = tid & 63, quad = l >> 4, l16 = l & 15;

    const f16* Qb = Qh + (bh * 1024 + q0) * 64;
    const f16* Kb = Kh + bh * 1024 * 64;
    const f16* Vb = Vt + bh * 64 * 1024;

    const f16x8 qa0 = *(const f16x8*)(Qb + l16 * 64 + quad * 8);
    const f16x8 qa1 = *(const f16x8*)(Qb + l16 * 64 + 32 + quad * 8);

    // phase 0: rel[q,r] = Q . embK_h ------------------------------
    for (int nf = w; nf < 9; nf += 4) {
        const int r0 = nf * 16;
        int rr = r0 + l16; if (rr > 128) rr = 128;
        const f16x8 b0 = *(const f16x8*)(embK + rr * 768 + h * 64 + quad * 8);
        const f16x8 b1 = *(const f16x8*)(embK + rr * 768 + h * 64 + 32 + quad * 8);
        f32x4 a = {};
        a = mfma16(qa0, b0, a);
        a = mfma16(qa1, b1, a);
#pragma unroll
        for (int r = 0; r < 4; r++)
            relw[(quad * 4 + r) * RST + r0 + l16] = (f16)a[r];
    }
    __syncthreads();

    // band-edge rel values in registers (broadcast reads)
    float rlo[4], rhi[4];
#pragma unroll
    for (int r = 0; r < 4; r++) {
        rlo[r] = (float)relw[(quad * 4 + r) * RST + 0];
        rhi[r] = (float)relw[(quad * 4 + r) * RST + 128];
    }

    // phase 1: e = exp((QK^T + rel)/8), unnormalized --------------
    float rs[4]  = {0.f, 0.f, 0.f, 0.f};
    float rt0[4] = {0.f, 0.f, 0.f, 0.f};
    float rt1[4] = {0.f, 0.f, 0.f, 0.f};
    for (int nf = 0; nf < 16; nf++) {
        const int kc = w * 256 + nf * 16;   // wave-uniform
        const f16x8 b0 = *(const f16x8*)(Kb + (kc + l16) * 64 + quad * 8);
        const f16x8 b1 = *(const f16x8*)(Kb + (kc + l16) * 64 + 32 + quad * 8);
        f32x4 a = {};
        a = mfma16(qa0, b0, a);
        a = mfma16(qa1, b1, a);
        const int kg = kc + l16;
        if (kc + 80 <= q0) {               // whole chunk below band: d = -64
#pragma unroll
            for (int r = 0; r < 4; r++) {
                const int row = quad * 4 + r;
                const float e = __expf((a[r] + rlo[r]) * 0.125f);
                sc[row * SCP + kg] = (f16)e;
                rs[r] += e; rt0[r] += e;
            }
        } else if (kc >= q0 + 80) {        // whole chunk above band: d = +64
#pragma unroll
            for (int r = 0; r < 4; r++) {
                const int row = quad * 4 + r;
                const float e = __expf((a[r] + rhi[r]) * 0.125f);
                sc[row * SCP + kg] = (f16)e;
                rs[r] += e; rt1[r] += e;
            }
        } else {
#pragma unroll
            for (int r = 0; r < 4; r++) {
                const int row = quad * 4 + r;
                const int qg = q0 + row;
                int d = kg - qg;
                d = (d < -64) ? -64 : (d > 64) ? 64 : d;
                const float e = __expf((a[r] + (float)relw[row * RST + d + 64]) * 0.125f);
                sc[row * SCP + kg] = (f16)e;
                rs[r] += e;
                rt0[r] += (kg <= qg - 64) ? e : 0.f;
                rt1[r] += (kg >= qg + 64) ? e : 0.f;
            }
        }
    }
#pragma unroll
    for (int r = 0; r < 4; r++)
        for (int o = 1; o < 16; o <<= 1) {
            rs[r]  += __shfl_xor(rs[r], o);
            rt0[r] += __shfl_xor(rt0[r], o);
            rt1[r] += __shfl_xor(rt1[r], o);
        }
    if (l16 == 0) {
#pragma unroll
        for (int r = 0; r < 4; r++) {
            red[0][w][quad * 4 + r] = rs[r];
            red[1][w][quad * 4 + r] = rt0[r];
            red[2][w][quad * 4 + r] = rt1[r];
        }
    }
    __syncthreads();
    if (tid < 16) {
        const float s = red[0][0][tid] + red[0][1][tid] + red[0][2][tid] + red[0][3][tid];
        invs[tid] = 1.f / s;
        tl0[tid] = red[1][0][tid] + red[1][1][tid] + red[1][2][tid] + red[1][3][tid];
        tl1[tid] = red[2][0][tid] + red[2][1][tid] + red[2][2][tid] + red[2][3][tid];
    }
    __syncthreads();

    // phase 3: attn -> global fp32 = sc * inv ---------------------
    {
        float* ab = attn + ((long)bh * 1024 + q0) * 1024;
#pragma unroll
        for (int rr = 0; rr < 4; rr++) {
            const int row = w * 4 + rr;
            const float inv = invs[row];
            const f16* p = sc + row * SCP;
            float* o = ab + (long)row * 1024;
#pragma unroll
            for (int jj = 0; jj < 4; jj++) {
                const int c = jj * 256 + l * 4;
                const f16x4 v = *(const f16x4*)(p + c);
                *(float4*)(o + c) = make_float4((float)v[0] * inv, (float)v[1] * inv,
                                                (float)v[2] * inv, (float)v[3] * inv);
            }
        }
    }
    // phase 4: build raw w into relw ------------------------------
    for (int idx = tid; idx < 16 * 160; idx += 256) {
        const int row = idx / 160, r = idx - row * 160;
        float v = 0.f;
        if (r == 0) v = tl0[row];
        else if (r == 128) v = tl1[row];
        else if (r < 128) {
            const int col = q0 + row + r - 64;
            if (col >= 0 && col < 1024) v = (float)sc[row * SCP + col];
        }
        relw[row * RST + r] = (f16)v;
    }
    __syncthreads();

    // phase 5: ctx = (attnU@V^T + wU@embV^T) * inv ----------------
    {
        f32x4 a = {};
        const f16* vrow = Vb + (w * 16 + l16) * 1024;
        for (int ks = 0; ks < 32; ks++) {
            const f16x8 af = *(const f16x8*)(sc + l16 * SCP + ks * 32 + quad * 8);
            const f16x8 bf = *(const f16x8*)(vrow + ks * 32 + quad * 8);
            a = mfma16(af, bf, a);
        }
        const f16* erow = embVt + (h * 64 + w * 16 + l16) * 160;
#pragma unroll
        for (int ks = 0; ks < 5; ks++) {
            const f16x8 af = *(const f16x8*)(relw + l16 * RST + ks * 32 + quad * 8);
            const f16x8 bf = *(const f16x8*)(erow + ks * 32 + quad * 8);
            a = mfma16(af, bf, a);
        }
#pragma unroll
        for (int r = 0; r < 4; r++) {
            const int row = quad * 4 + r;
            const int qg = q0 + row;
            ctx[(b * 1024 + qg) * 768 + h * 64 + w * 16 + l16] = (f16)(a[r] * invs[row]);
        }
    }
}

// ---------------------------------------------------------------- launch
extern "C" void kernel_launch(void* const* d_in, const int* in_sizes, int n_in,
                              void* d_out, int out_size, void* d_ws, size_t ws_size,
                              hipStream_t stream) {
    const float* q_in = (const float*)d_in[0];
    const float* k_in = (const float*)d_in[1];
    const float* v_in = (const float*)d_in[2];
    const float* WQw  = (const float*)d_in[3];
    const float* WQb  = (const float*)d_in[4];
    const float* WKw  = (const float*)d_in[5];
    const float* WKb  = (const float*)d_in[6];
    const float* WVw  = (const float*)d_in[7];
    const float* WVb  = (const float*)d_in[8];
    const float* WOw  = (const float*)d_in[9];
    const float* WOb  = (const float*)d_in[10];
    const float* embK = (const float*)d_in[11];
    const float* embV = (const float*)d_in[12];

    char*  ws  = (char*)d_ws;
    size_t off = 0;
    auto nxt = [&](size_t n) {
        char* p = ws + off;
        off += (n + 255) & ~(size_t)255;
        return p;
    };
    f16* Wqb   = (f16*)nxt(589824 * 2);
    f16* Wkb   = (f16*)nxt(589824 * 2);
    f16* Wvb   = (f16*)nxt(589824 * 2);
    f16* Wob   = (f16*)nxt(589824 * 2);
    f16* embKb = (f16*)nxt(99072 * 2);
    f16* embVt = (f16*)nxt(122880 * 2);
    f16* Qh    = (f16*)nxt(3145728 * 2);
    f16* Kh    = (f16*)nxt(3145728 * 2);
    f16* Vh    = (f16*)nxt(3145728 * 2);
    f16* Vt    = (f16*)nxt(3145728 * 2);
    f16* ctx   = (f16*)nxt(3145728 * 2);
    (void)ws_size; (void)in_sizes; (void)n_in; (void)out_size;

    ConvArgs ca;
    ca.src[0] = WQw; ca.src[1] = WKw; ca.src[2] = WVw; ca.src[3] = WOw; ca.src[4] = embK;
    ca.dst[0] = Wqb; ca.dst[1] = Wkb; ca.dst[2] = Wvb; ca.dst[3] = Wob; ca.dst[4] = embKb;

    k_convw<<<dim3(1200), dim3(256), 0, stream>>>(ca);
    k_embvt<<<dim3(480), dim3(256), 0, stream>>>(embV, embVt);
    k_gemm_qkv<<<dim3(32, 18), dim3(256), 0, stream>>>(
        q_in, k_in, v_in, Wqb, Wkb, Wvb, WQb, WKb, WVb, Qh, Kh, Vh);
    k_vt<<<dim3(16, 48), dim3(256), 0, stream>>>(Vh, Vt);
    float* attn = (float*)d_out + 3145728;
    k_attn<<<dim3(64, 48), dim3(256), 0, stream>>>(Qh, Kh, Vt, embKb, embVt, attn, ctx);
    k_gemm_out<<<dim3(64, 6), dim3(256), 0, stream>>>(ctx, Wob, WOb, (float*)d_out);
}

// Round 5
// 399.357 us; speedup vs baseline: 1.0114x; 1.0114x over previous
//
#include <hip/hip_runtime.h>

typedef _Float16 f16;
typedef _Float16 f16x4 __attribute__((ext_vector_type(4)));
typedef _Float16 f16x8 __attribute__((ext_vector_type(8)));
typedef float    f32x4 __attribute__((ext_vector_type(4)));

#define DEV static __device__ __forceinline__

DEV f32x4 mfma16(f16x8 a, f16x8 b, f32x4 c) {
    return __builtin_amdgcn_mfma_f32_16x16x32_f16(a, b, c, 0, 0, 0);
}

// async global->LDS, 16B per lane, dest = wave-uniform base + lane*16
DEV void gload16(const f16* g, f16* l) {
    __builtin_amdgcn_global_load_lds(
        (const __attribute__((address_space(1))) unsigned int*)g,
        (__attribute__((address_space(3))) unsigned int*)l,
        16, 0, 0);
}

// B=4, S=1024, D=768, H=12, DH=64, R=129 (padded 160/168 for k-steps)

// ---------------------------------------------------------------- convert
// q,k,v activations + 4 weights + embK: fp32 -> f16 (all L3-resident after)
struct ConvArgs {
    const float* src[8];
    f16*         dst[8];
};

__global__ __launch_bounds__(256) void k_convert(ConvArgs a) {
    const int seg[9] = {0, 786432, 1572864, 2359296, 2506752, 2654208,
                        2801664, 2949120, 2973888};
    for (int i = blockIdx.x * 256 + threadIdx.x; i < 2973888; i += gridDim.x * 256) {
        int s = 0;
        while (i >= seg[s + 1]) s++;
        const int j = i - seg[s];
        const float4 v = ((const float4*)a.src[s])[j];
        f16x4 o;
        o[0] = (f16)v.x; o[1] = (f16)v.y; o[2] = (f16)v.z; o[3] = (f16)v.w;
        ((f16x4*)a.dst[s])[j] = o;
    }
}

// embVt[h][dh][r] = embV[r, h*64+dh] for r<129 else 0
__global__ __launch_bounds__(256) void k_embvt(const float* __restrict__ embV,
                                               f16* __restrict__ dst) {
    const int idx = blockIdx.x * 256 + threadIdx.x;
    if (idx >= 12 * 64 * 160) return;
    const int r  = idx % 160;
    const int dh = (idx / 160) % 64;
    const int h  = idx / (160 * 64);
    float v = 0.f;
    if (r < 129) v = embV[r * 768 + h * 64 + dh];
    dst[idx] = (f16)v;
}

// ---------------------------------------------------------------- QKV GEMM
// 128x128 tile, BK=32, fully-async f16 staging (m97 shape).
// XOR chunk swizzle: slot (r,c) holds global chunk c^s(r), s(r)=((r)^(r>>2))&3;
// reader chunk = quad ^ s(l16). Max 2-way bank aliasing (free, m136).
__global__ __launch_bounds__(256) void k_gemm_qkv(
    const f16* __restrict__ aq, const f16* __restrict__ ak, const f16* __restrict__ av,
    const f16* __restrict__ wq, const f16* __restrict__ wk, const f16* __restrict__ wv,
    const float* __restrict__ bq, const float* __restrict__ bk, const float* __restrict__ bv,
    f16* __restrict__ Qh, f16* __restrict__ Kh, f16* __restrict__ Vh) {
    __shared__ __align__(16) f16 As[128 * 32];
    __shared__ __align__(16) f16 Bs[128 * 32];

    const int t  = blockIdx.y / 6;           // 0:Q 1:K 2:V
    const int n0 = (blockIdx.y % 6) * 128;   // within 768
    const int m0 = blockIdx.x * 128;
    const f16*   X    = (t == 0) ? aq : (t == 1) ? ak : av;
    const f16*   W    = (t == 0) ? wq : (t == 1) ? wk : wv;
    const float* bias = (t == 0) ? bq : (t == 1) ? bk : bv;

    const int tid = threadIdx.x;
    const int w = tid >> 6, l = tid & 63, quad = l >> 4, l16 = l & 15;
    const int wr = w >> 1, wc = w & 1;
    const int rl = l >> 2, cc = l & 3;
    const int csrc = (cc ^ ((rl ^ (rl >> 2)) & 3)) * 8;
    const f16* gA = X + (size_t)(m0 + w * 32 + rl) * 768 + csrc;
    const f16* gB = W + (size_t)(n0 + w * 32 + rl) * 768 + csrc;
    f16* lA0 = As + (w * 32) * 32;
    f16* lA1 = As + (w * 32 + 16) * 32;
    f16* lB0 = Bs + (w * 32) * 32;
    f16* lB1 = Bs + (w * 32 + 16) * 32;
    const int xsw = (quad ^ ((l16 ^ (l16 >> 2)) & 3)) * 8;

    f32x4 acc[4][4] = {};

    for (int k0 = 0; k0 < 768; k0 += 32) {
        __syncthreads();
        gload16(gA + k0, lA0);
        gload16(gA + k0 + 16 * 768, lA1);
        gload16(gB + k0, lB0);
        gload16(gB + k0 + 16 * 768, lB1);
        __syncthreads();
        f16x8 af[4], bf[4];
#pragma unroll
        for (int i = 0; i < 4; i++)
            af[i] = *(const f16x8*)(As + (wr * 64 + i * 16 + l16) * 32 + xsw);
#pragma unroll
        for (int i = 0; i < 4; i++)
            bf[i] = *(const f16x8*)(Bs + (wc * 64 + i * 16 + l16) * 32 + xsw);
#pragma unroll
        for (int i = 0; i < 4; i++)
#pragma unroll
            for (int j = 0; j < 4; j++)
                acc[i][j] = mfma16(af[i], bf[j], acc[i][j]);
    }

    // epilogue: C/D layout col=lane&15, row=quad*4+reg; store [bh][s][dh]
    f16* dst = (t == 0) ? Qh : (t == 1) ? Kh : Vh;
#pragma unroll
    for (int j = 0; j < 4; j++) {
        const int   nj = n0 + wc * 64 + j * 16 + l16;  // 0..767
        const float bb = bias[nj];
        const int   h = nj >> 6, dh = nj & 63;
#pragma unroll
        for (int i = 0; i < 4; i++) {
            const int mb = m0 + wr * 64 + i * 16 + quad * 4;
            const int b = mb >> 10, s = mb & 1023;
            const int base = ((b * 12 + h) * 1024 + s) * 64 + dh;
#pragma unroll
            for (int r = 0; r < 4; r++)
                dst[base + r * 64] = (f16)(acc[i][j][r] + bb);
        }
    }
}

// ---------------------------------------------------------------- V transpose
// Vh[bh][s][dh] -> Vt[bh][dh][s], 64x64 tiles via LDS (stride 72 pad)
__global__ __launch_bounds__(256) void k_vt(const f16* __restrict__ Vh,
                                            f16* __restrict__ Vt) {
    __shared__ __align__(16) f16 ld[64 * 72];
    const int s0 = blockIdx.x * 64, bh = blockIdx.y;
    const int tid = threadIdx.x;
    const int sr = tid >> 2;   // s-row 0..63 (coalesced global read)
    const int ch = tid & 3;    // 16-col chunk
    const f16* src = Vh + ((size_t)bh * 1024 + s0 + sr) * 64 + ch * 16;
    const f16x8 v0 = *(const f16x8*)(src);
    const f16x8 v1 = *(const f16x8*)(src + 8);
#pragma unroll
    for (int c = 0; c < 8; c++) ld[(ch * 16 + c) * 72 + sr] = v0[c];
#pragma unroll
    for (int c = 0; c < 8; c++) ld[(ch * 16 + 8 + c) * 72 + sr] = v1[c];
    __syncthreads();
    const int dh = tid >> 2;
    f16* dst = Vt + ((size_t)bh * 64 + dh) * 1024 + s0 + ch * 16;
    *(f16x8*)(dst)     = *(const f16x8*)(ld + dh * 72 + ch * 16);
    *(f16x8*)(dst + 8) = *(const f16x8*)(ld + dh * 72 + ch * 16 + 8);
}

// ---------------------------------------------------------------- out GEMM
// 64m x 128n tiles -> grid 64x6 = 384 blocks. Wave: 32m x 64n, acc[2][4].
__global__ __launch_bounds__(256) void k_gemm_out(
    const f16* __restrict__ Xin, const f16* __restrict__ Win,
    const float* __restrict__ bias, float* __restrict__ out) {
    __shared__ __align__(16) f16 As[64 * 32];
    __shared__ __align__(16) f16 Bs[128 * 32];

    const int m0 = blockIdx.x * 64;
    const int n0 = blockIdx.y * 128;
    const int tid = threadIdx.x;
    const int w = tid >> 6, l = tid & 63, quad = l >> 4, l16 = l & 15;
    const int mh = w & 1, nh = w >> 1;
    const int rl = l >> 2, cc = l & 3;
    const int csrc = (cc ^ ((rl ^ (rl >> 2)) & 3)) * 8;
    const f16* gA = Xin + (size_t)(m0 + w * 16 + rl) * 768 + csrc;
    const f16* gB = Win + (size_t)(n0 + w * 32 + rl) * 768 + csrc;
    f16* lA  = As + (w * 16) * 32;
    f16* lB0 = Bs + (w * 32) * 32;
    f16* lB1 = Bs + (w * 32 + 16) * 32;
    const int xsw = (quad ^ ((l16 ^ (l16 >> 2)) & 3)) * 8;

    f32x4 acc[2][4] = {};

    for (int k0 = 0; k0 < 768; k0 += 32) {
        __syncthreads();
        gload16(gA + k0, lA);
        gload16(gB + k0, lB0);
        gload16(gB + k0 + 16 * 768, lB1);
        __syncthreads();
        f16x8 af[2], bf[4];
#pragma unroll
        for (int i = 0; i < 2; i++)
            af[i] = *(const f16x8*)(As + (mh * 32 + i * 16 + l16) * 32 + xsw);
#pragma unroll
        for (int j = 0; j < 4; j++)
            bf[j] = *(const f16x8*)(Bs + (nh * 64 + j * 16 + l16) * 32 + xsw);
#pragma unroll
        for (int i = 0; i < 2; i++)
#pragma unroll
            for (int j = 0; j < 4; j++)
                acc[i][j] = mfma16(af[i], bf[j], acc[i][j]);
    }

#pragma unroll
    for (int j = 0; j < 4; j++) {
        const int   nj = n0 + nh * 64 + j * 16 + l16;
        const float bb = bias[nj];
#pragma unroll
        for (int i = 0; i < 2; i++) {
            const int mb = m0 + mh * 32 + i * 16 + quad * 4;
#pragma unroll
            for (int r = 0; r < 4; r++)
                out[(size_t)(mb + r) * 768 + nj] = acc[i][j][r] + bb;
        }
    }
}

// ---------------------------------------------------------------- fused attention
// One block = (b,h, 16 q-rows). No-max softmax fused into score phase.
// Band-aware rel add: a 16-col chunk fully below/above the +-64 band
// (wave-uniform test) uses register rlo/rhi instead of the LDS gather.
// relw stride 168 (4-way worst-case residual conflicts).
constexpr int SCP = 1032;   // score row stride (f16)
constexpr int RST = 168;    // relw row stride (f16)

__global__ __launch_bounds__(256) void k_attn(
    const f16* __restrict__ Qh, const f16* __restrict__ Kh, const f16* __restrict__ Vt,
    const f16* __restrict__ embK, const f16* __restrict__ embVt,
    float* __restrict__ attn, f16* __restrict__ ctx) {
    __shared__ __align__(16) f16 sc[16 * SCP];     // 33,024 B
    __shared__ __align__(16) f16 relw[16 * RST];   //  5,376 B
    __shared__ float red[3][4][16];
    __shared__ float invs[16], tl0[16], tl1[16];

    const int qt = blockIdx.x, bh = blockIdx.y;
    const int b = bh / 12, h = bh % 12;
    const int q0 = qt * 16;
    const int tid = threadIdx.x;
    const int w = tid >> 6, l = tid & 63, quad = l >> 4, l16 = l & 15;

    const f16* Qb = Qh + (bh * 1024 + q0) * 64;
    const f16* Kb = Kh + bh * 1024 * 64;
    const f16* Vb = Vt + bh * 64 * 1024;

    const f16x8 qa0 = *(const f16x8*)(Qb + l16 * 64 + quad * 8);
    const f16x8 qa1 = *(const f16x8*)(Qb + l16 * 64 + 32 + quad * 8);

    // phase 0: rel[q,r] = Q . embK_h ------------------------------
    for (int nf = w; nf < 9; nf += 4) {
        const int r0 = nf * 16;
        int rr = r0 + l16; if (rr > 128) rr = 128;
        const f16x8 b0 = *(const f16x8*)(embK + rr * 768 + h * 64 + quad * 8);
        const f16x8 b1 = *(const f16x8*)(embK + rr * 768 + h * 64 + 32 + quad * 8);
        f32x4 a = {};
        a = mfma16(qa0, b0, a);
        a = mfma16(qa1, b1, a);
#pragma unroll
        for (int r = 0; r < 4; r++)
            relw[(quad * 4 + r) * RST + r0 + l16] = (f16)a[r];
    }
    __syncthreads();

    // band-edge rel values in registers (broadcast reads)
    float rlo[4], rhi[4];
#pragma unroll
    for (int r = 0; r < 4; r++) {
        rlo[r] = (float)relw[(quad * 4 + r) * RST + 0];
        rhi[r] = (float)relw[(quad * 4 + r) * RST + 128];
    }

    // phase 1: e = exp((QK^T + rel)/8), unnormalized --------------
    float rs[4]  = {0.f, 0.f, 0.f, 0.f};
    float rt0[4] = {0.f, 0.f, 0.f, 0.f};
    float rt1[4] = {0.f, 0.f, 0.f, 0.f};
    for (int nf = 0; nf < 16; nf++) {
        const int kc = w * 256 + nf * 16;   // wave-uniform
        const f16x8 b0 = *(const f16x8*)(Kb + (kc + l16) * 64 + quad * 8);
        const f16x8 b1 = *(const f16x8*)(Kb + (kc + l16) * 64 + 32 + quad * 8);
        f32x4 a = {};
        a = mfma16(qa0, b0, a);
        a = mfma16(qa1, b1, a);
        const int kg = kc + l16;
        if (kc + 80 <= q0) {               // whole chunk below band: d = -64
#pragma unroll
            for (int r = 0; r < 4; r++) {
                const int row = quad * 4 + r;
                const float e = __expf((a[r] + rlo[r]) * 0.125f);
                sc[row * SCP + kg] = (f16)e;
                rs[r] += e; rt0[r] += e;
            }
        } else if (kc >= q0 + 80) {        // whole chunk above band: d = +64
#pragma unroll
            for (int r = 0; r < 4; r++) {
                const int row = quad * 4 + r;
                const float e = __expf((a[r] + rhi[r]) * 0.125f);
                sc[row * SCP + kg] = (f16)e;
                rs[r] += e; rt1[r] += e;
            }
        } else {
#pragma unroll
            for (int r = 0; r < 4; r++) {
                const int row = quad * 4 + r;
                const int qg = q0 + row;
                int d = kg - qg;
                d = (d < -64) ? -64 : (d > 64) ? 64 : d;
                const float e = __expf((a[r] + (float)relw[row * RST + d + 64]) * 0.125f);
                sc[row * SCP + kg] = (f16)e;
                rs[r] += e;
                rt0[r] += (kg <= qg - 64) ? e : 0.f;
                rt1[r] += (kg >= qg + 64) ? e : 0.f;
            }
        }
    }
#pragma unroll
    for (int r = 0; r < 4; r++)
        for (int o = 1; o < 16; o <<= 1) {
            rs[r]  += __shfl_xor(rs[r], o);
            rt0[r] += __shfl_xor(rt0[r], o);
            rt1[r] += __shfl_xor(rt1[r], o);
        }
    if (l16 == 0) {
#pragma unroll
        for (int r = 0; r < 4; r++) {
            red[0][w][quad * 4 + r] = rs[r];
            red[1][w][quad * 4 + r] = rt0[r];
            red[2][w][quad * 4 + r] = rt1[r];
        }
    }
    __syncthreads();
    if (tid < 16) {
        const float s = red[0][0][tid] + red[0][1][tid] + red[0][2][tid] + red[0][3][tid];
        invs[tid] = 1.f / s;
        tl0[tid] = red[1][0][tid] + red[1][1][tid] + red[1][2][tid] + red[1][3][tid];
        tl1[tid] = red[2][0][tid] + red[2][1][tid] + red[2][2][tid] + red[2][3][tid];
    }
    __syncthreads();

    // phase 3: attn -> global fp32 = sc * inv ---------------------
    {
        float* ab = attn + ((long)bh * 1024 + q0) * 1024;
#pragma unroll
        for (int rr = 0; rr < 4; rr++) {
            const int row = w * 4 + rr;
            const float inv = invs[row];
            const f16* p = sc + row * SCP;
            float* o = ab + (long)row * 1024;
#pragma unroll
            for (int jj = 0; jj < 4; jj++) {
                const int c = jj * 256 + l * 4;
                const f16x4 v = *(const f16x4*)(p + c);
                *(float4*)(o + c) = make_float4((float)v[0] * inv, (float)v[1] * inv,
                                                (float)v[2] * inv, (float)v[3] * inv);
            }
        }
    }
    // phase 4: build raw w into relw ------------------------------
    for (int idx = tid; idx < 16 * 160; idx += 256) {
        const int row = idx / 160, r = idx - row * 160;
        float v = 0.f;
        if (r == 0) v = tl0[row];
        else if (r == 128) v = tl1[row];
        else if (r < 128) {
            const int col = q0 + row + r - 64;
            if (col >= 0 && col < 1024) v = (float)sc[row * SCP + col];
        }
        relw[row * RST + r] = (f16)v;
    }
    __syncthreads();

    // phase 5: ctx = (attnU@V^T + wU@embV^T) * inv ----------------
    {
        f32x4 a = {};
        const f16* vrow = Vb + (w * 16 + l16) * 1024;
        for (int ks = 0; ks < 32; ks++) {
            const f16x8 af = *(const f16x8*)(sc + l16 * SCP + ks * 32 + quad * 8);
            const f16x8 bf = *(const f16x8*)(vrow + ks * 32 + quad * 8);
            a = mfma16(af, bf, a);
        }
        const f16* erow = embVt + (h * 64 + w * 16 + l16) * 160;
#pragma unroll
        for (int ks = 0; ks < 5; ks++) {
            const f16x8 af = *(const f16x8*)(relw + l16 * RST + ks * 32 + quad * 8);
            const f16x8 bf = *(const f16x8*)(erow + ks * 32 + quad * 8);
            a = mfma16(af, bf, a);
        }
#pragma unroll
        for (int r = 0; r < 4; r++) {
            const int row = quad * 4 + r;
            const int qg = q0 + row;
            ctx[(b * 1024 + qg) * 768 + h * 64 + w * 16 + l16] = (f16)(a[r] * invs[row]);
        }
    }
}

// ---------------------------------------------------------------- launch
extern "C" void kernel_launch(void* const* d_in, const int* in_sizes, int n_in,
                              void* d_out, int out_size, void* d_ws, size_t ws_size,
                              hipStream_t stream) {
    const float* q_in = (const float*)d_in[0];
    const float* k_in = (const float*)d_in[1];
    const float* v_in = (const float*)d_in[2];
    const float* WQw  = (const float*)d_in[3];
    const float* WQb  = (const float*)d_in[4];
    const float* WKw  = (const float*)d_in[5];
    const float* WKb  = (const float*)d_in[6];
    const float* WVw  = (const float*)d_in[7];
    const float* WVb  = (const float*)d_in[8];
    const float* WOw  = (const float*)d_in[9];
    const float* WOb  = (const float*)d_in[10];
    const float* embK = (const float*)d_in[11];
    const float* embV = (const float*)d_in[12];

    char*  ws  = (char*)d_ws;
    size_t off = 0;
    auto nxt = [&](size_t n) {
        char* p = ws + off;
        off += (n + 255) & ~(size_t)255;
        return p;
    };
    f16* qb    = (f16*)nxt(3145728 * 2);
    f16* kb    = (f16*)nxt(3145728 * 2);
    f16* vb    = (f16*)nxt(3145728 * 2);
    f16* Wqb   = (f16*)nxt(589824 * 2);
    f16* Wkb   = (f16*)nxt(589824 * 2);
    f16* Wvb   = (f16*)nxt(589824 * 2);
    f16* Wob   = (f16*)nxt(589824 * 2);
    f16* embKb = (f16*)nxt(99072 * 2);
    f16* embVt = (f16*)nxt(122880 * 2);
    f16* Qh    = (f16*)nxt(3145728 * 2);
    f16* Kh    = (f16*)nxt(3145728 * 2);
    f16* Vh    = (f16*)nxt(3145728 * 2);
    f16* Vt    = (f16*)nxt(3145728 * 2);
    f16* ctx   = (f16*)nxt(3145728 * 2);
    (void)ws_size; (void)in_sizes; (void)n_in; (void)out_size;

    ConvArgs ca;
    ca.src[0] = q_in; ca.src[1] = k_in; ca.src[2] = v_in;
    ca.src[3] = WQw;  ca.src[4] = WKw;  ca.src[5] = WVw;
    ca.src[6] = WOw;  ca.src[7] = embK;
    ca.dst[0] = qb;   ca.dst[1] = kb;   ca.dst[2] = vb;
    ca.dst[3] = Wqb;  ca.dst[4] = Wkb;  ca.dst[5] = Wvb;
    ca.dst[6] = Wob;  ca.dst[7] = embKb;

    k_convert<<<dim3(2048), dim3(256), 0, stream>>>(ca);
    k_embvt<<<dim3(480), dim3(256), 0, stream>>>(embV, embVt);
    k_gemm_qkv<<<dim3(32, 18), dim3(256), 0, stream>>>(
        qb, kb, vb, Wqb, Wkb, Wvb, WQb, WKb, WVb, Qh, Kh, Vh);
    k_vt<<<dim3(16, 48), dim3(256), 0, stream>>>(Vh, Vt);
    float* attn = (float*)d_out + 3145728;
    k_attn<<<dim3(64, 48), dim3(256), 0, stream>>>(Qh, Kh, Vt, embKb, embVt, attn, ctx);
    k_gemm_out<<<dim3(64, 6), dim3(256), 0, stream>>>(ctx, Wob, WOb, (float*)d_out);
}